// Round 4
// baseline (137.639 us; speedup 1.0000x reference)
//
#include <hip/hip_runtime.h>
#include <hip/hip_bf16.h>
#include <cstdint>

#define KD 512
#define BM 256
#define NT 512
#define LDB 264          // B row stride in ushorts (528 B)
#define NSPLIT 63
#define NNODES 127

typedef __attribute__((ext_vector_type(8))) short bf16x8;
typedef __attribute__((ext_vector_type(4))) float f32x4;

#define MFMA_B16(a, b, c) __builtin_amdgcn_mfma_f32_16x16x32_bf16(a, b, c, 0, 0, 0)

__device__ __forceinline__ unsigned short f2bf(float f) {
    return __builtin_bit_cast(unsigned short, __float2bfloat16(f));
}
__device__ __forceinline__ float bf2f(unsigned short h) {
    return __builtin_bit_cast(float, (unsigned)h << 16);
}
__device__ __forceinline__ unsigned pack2(float f0, float f1) {
    return (unsigned)f2bf(f0) | ((unsigned)f2bf(f1) << 16);
}

// 8 fp32 (two float4) -> bf16 hi8 + residual lo8. Named scalars only — no
// address-taken locals, so everything stays in VGPRs.
__device__ __forceinline__ void cvt8(float4 a, float4 b, bf16x8& hi, bf16x8& lo) {
    const unsigned short h0 = f2bf(a.x), h1 = f2bf(a.y), h2 = f2bf(a.z), h3 = f2bf(a.w);
    const unsigned short h4 = f2bf(b.x), h5 = f2bf(b.y), h6 = f2bf(b.z), h7 = f2bf(b.w);
    uint4 H = make_uint4((unsigned)h0 | ((unsigned)h1 << 16),
                         (unsigned)h2 | ((unsigned)h3 << 16),
                         (unsigned)h4 | ((unsigned)h5 << 16),
                         (unsigned)h6 | ((unsigned)h7 << 16));
    uint4 L = make_uint4(pack2(a.x - bf2f(h0), a.y - bf2f(h1)),
                         pack2(a.z - bf2f(h2), a.w - bf2f(h3)),
                         pack2(b.x - bf2f(h4), b.y - bf2f(h5)),
                         pack2(b.z - bf2f(h6), b.w - bf2f(h7)));
    hi = __builtin_bit_cast(bf16x8, H);
    lo = __builtin_bit_cast(bf16x8, L);
}

// DFS tree walk: node T's running path-min qt; children 2T+1 (min(qt,s)) and
// 2T+2 (min(qt,-s)). Live registers = recursion depth (~6), all indices static.
template<int T>
__device__ __forceinline__ void tree_walk(float qt, const float* __restrict__ srow,
                                          float* __restrict__ orow, int part) {
    const float s  = srow[T];
    const float ql = fminf(qt, s);
    const float qr = fminf(qt, -s);
    if (((2 * T + 1) >> 5) == part) orow[2 * T + 1] = fminf(fmaxf(ql, 0.f), 1.f);
    if (((2 * T + 2) >> 5) == part) orow[2 * T + 2] = fminf(fmaxf(qr, 0.f), 1.f);
    if constexpr (2 * T + 1 < NSPLIT) tree_walk<2 * T + 1>(ql, srow, orow, part);
    if constexpr (2 * T + 2 < NSPLIT) tree_walk<2 * T + 2>(qr, srow, orow, part);
}

__global__ __launch_bounds__(NT, 4)
void lt_mfma3(const float* __restrict__ x, const float* __restrict__ A,
              float* __restrict__ out) {
    __shared__ __align__(16) unsigned short sm[2 * 64 * LDB];   // 67584 B
    unsigned short* bh = sm;
    unsigned short* bl = sm + 64 * LDB;
    float* fl = reinterpret_cast<float*>(sm);

    const int tid  = threadIdx.x;
    const int wave = tid >> 6;
    const int lane = tid & 63;
    const int fr   = lane & 15;
    const int kb   = (lane >> 4) * 8;
    const int r0   = blockIdx.x * BM;
    const int m0   = wave * 32;

    const float* xr0p = x + (size_t)(r0 + m0 + fr) * KD + kb;
    const float* xr1p = xr0p + 16 * KD;

    const int brow = tid >> 3;
    const int bkj  = (tid & 7) * 32;
    const float* ap = A + (size_t)brow * KD + bkj;

    f32x4 acc[2][4];
#pragma unroll
    for (int i = 0; i < 2; ++i)
#pragma unroll
        for (int j = 0; j < 4; ++j) acc[i][j] = (f32x4)(0.f);

    // prologue: tile-0 x fragments into named regs
    float4 c0a = *reinterpret_cast<const float4*>(xr0p);
    float4 c0b = *reinterpret_cast<const float4*>(xr0p + 4);
    float4 c1a = *reinterpret_cast<const float4*>(xr1p);
    float4 c1b = *reinterpret_cast<const float4*>(xr1p + 4);

#pragma unroll
    for (int h = 0; h < 2; ++h) {
        // ---- stage B half h (hi/lo split), named regs only
#pragma unroll
        for (int p8 = 0; p8 < 4; ++p8) {
            float4 a = make_float4(0.f, 0.f, 0.f, 0.f);
            float4 b = make_float4(0.f, 0.f, 0.f, 0.f);
            if (brow < NSPLIT) {
                a = *reinterpret_cast<const float4*>(ap + h * 256 + p8 * 8);
                b = *reinterpret_cast<const float4*>(ap + h * 256 + p8 * 8 + 4);
            }
            bf16x8 hi, lo;
            cvt8(a, b, hi, lo);
            *reinterpret_cast<bf16x8*>(&bh[brow * LDB + bkj + p8 * 8]) = hi;
            *reinterpret_cast<bf16x8*>(&bl[brow * LDB + bkj + p8 * 8]) = lo;
        }
        __syncthreads();

        // ---- 8 K-tiles of 32, barrier-free
#pragma unroll
        for (int t = 0; t < 8; ++t) {
            const int gt = h * 8 + t;
            float4 n0a, n0b, n1a, n1b;
            if (gt + 1 < 16) {             // issue next tile's loads first
                n0a = *reinterpret_cast<const float4*>(xr0p + (gt + 1) * 32);
                n0b = *reinterpret_cast<const float4*>(xr0p + (gt + 1) * 32 + 4);
                n1a = *reinterpret_cast<const float4*>(xr1p + (gt + 1) * 32);
                n1b = *reinterpret_cast<const float4*>(xr1p + (gt + 1) * 32 + 4);
            }
            bf16x8 ah0, al0, ah1, al1;
            cvt8(c0a, c0b, ah0, al0);
            cvt8(c1a, c1b, ah1, al1);

            const int boff = fr * LDB + t * 32 + kb;
            bf16x8 bv0 = *reinterpret_cast<const bf16x8*>(&bh[boff]);
            bf16x8 bv1 = *reinterpret_cast<const bf16x8*>(&bh[boff + 16 * LDB]);
            bf16x8 bv2 = *reinterpret_cast<const bf16x8*>(&bh[boff + 32 * LDB]);
            bf16x8 bv3 = *reinterpret_cast<const bf16x8*>(&bh[boff + 48 * LDB]);

            // hh: 8 MFMAs (acc reuse distance 8)
            acc[0][0] = MFMA_B16(ah0, bv0, acc[0][0]);
            acc[1][0] = MFMA_B16(ah1, bv0, acc[1][0]);
            acc[0][1] = MFMA_B16(ah0, bv1, acc[0][1]);
            acc[1][1] = MFMA_B16(ah1, bv1, acc[1][1]);
            acc[0][2] = MFMA_B16(ah0, bv2, acc[0][2]);
            acc[1][2] = MFMA_B16(ah1, bv2, acc[1][2]);
            acc[0][3] = MFMA_B16(ah0, bv3, acc[0][3]);
            acc[1][3] = MFMA_B16(ah1, bv3, acc[1][3]);
            // lh: x_lo * B_hi (reuses bv*)
            acc[0][0] = MFMA_B16(al0, bv0, acc[0][0]);
            acc[1][0] = MFMA_B16(al1, bv0, acc[1][0]);
            acc[0][1] = MFMA_B16(al0, bv1, acc[0][1]);
            acc[1][1] = MFMA_B16(al1, bv1, acc[1][1]);
            acc[0][2] = MFMA_B16(al0, bv2, acc[0][2]);
            acc[1][2] = MFMA_B16(al1, bv2, acc[1][2]);
            acc[0][3] = MFMA_B16(al0, bv3, acc[0][3]);
            acc[1][3] = MFMA_B16(al1, bv3, acc[1][3]);
            // hl: x_hi * B_lo
            bv0 = *reinterpret_cast<const bf16x8*>(&bl[boff]);
            bv1 = *reinterpret_cast<const bf16x8*>(&bl[boff + 16 * LDB]);
            bv2 = *reinterpret_cast<const bf16x8*>(&bl[boff + 32 * LDB]);
            bv3 = *reinterpret_cast<const bf16x8*>(&bl[boff + 48 * LDB]);
            acc[0][0] = MFMA_B16(ah0, bv0, acc[0][0]);
            acc[1][0] = MFMA_B16(ah1, bv0, acc[1][0]);
            acc[0][1] = MFMA_B16(ah0, bv1, acc[0][1]);
            acc[1][1] = MFMA_B16(ah1, bv1, acc[1][1]);
            acc[0][2] = MFMA_B16(ah0, bv2, acc[0][2]);
            acc[1][2] = MFMA_B16(ah1, bv2, acc[1][2]);
            acc[0][3] = MFMA_B16(ah0, bv3, acc[0][3]);
            acc[1][3] = MFMA_B16(ah1, bv3, acc[1][3]);

            if (gt + 1 < 16) { c0a = n0a; c0b = n0b; c1a = n1a; c1b = n1b; }
        }
        __syncthreads();
    }

    // ---- epilogue (warea per-wave private after the barrier above; no more syncs)
    const int drow = (lane >> 4) * 4;      // D frag: row = drow+rg, col = fr
    float* warea = fl + wave * 16 * 65;
    const int trow = lane >> 2;            // 4 lanes per row
    const int part = lane & 3;             // lane stores nodes [part*32, part*32+32)

#pragma unroll
    for (int ph = 0; ph < 2; ++ph) {
#pragma unroll
        for (int nf = 0; nf < 4; ++nf)
#pragma unroll
            for (int rg = 0; rg < 4; ++rg)
                warea[(drow + rg) * 65 + nf * 16 + fr] = acc[ph][nf][rg];

        const float* srowp = warea + trow * 65;
        float* orow = out + (size_t)(r0 + m0 + ph * 16 + trow) * NNODES;
        if (part == 0) orow[0] = 1.f;
        tree_walk<0>(1.f, srowp, orow, part);
        // in-wave LDS write->read ordering is handled by lgkmcnt; per-wave area
    }
}

extern "C" void kernel_launch(void* const* d_in, const int* in_sizes, int n_in,
                              void* d_out, int out_size, void* d_ws, size_t ws_size,
                              hipStream_t stream) {
    const float* x = (const float*)d_in[0];   // [131072, 512]
    const float* A = (const float*)d_in[1];   // [63, 512]
    float* out = (float*)d_out;               // [131072, 127]
    const int nrows = in_sizes[0] / KD;       // 131072
    const int grid = nrows / BM;              // 512 blocks = 2/CU
    lt_mfma3<<<dim3(grid), dim3(NT), 0, stream>>>(x, A, out);
}

// Round 5
// 89.018 us; speedup vs baseline: 1.5462x; 1.5462x over previous
//
#include <hip/hip_runtime.h>
#include <hip/hip_bf16.h>
#include <cstdint>

#define KD 512
#define BM 128
#define NT 256
#define NSPLIT 63
#define NNODES 127

typedef __attribute__((ext_vector_type(8))) short bf16x8;
typedef __attribute__((ext_vector_type(4))) float f32x4;

#define MFMA_B16(a, b, c) __builtin_amdgcn_mfma_f32_16x16x32_bf16(a, b, c, 0, 0, 0)

__device__ __forceinline__ unsigned short f2bf(float f) {
    return __builtin_bit_cast(unsigned short, __float2bfloat16(f));
}
__device__ __forceinline__ float bf2f(unsigned short h) {
    return __builtin_bit_cast(float, (unsigned)h << 16);
}
__device__ __forceinline__ unsigned pack2(float f0, float f1) {
    return (unsigned)f2bf(f0) | ((unsigned)f2bf(f1) << 16);
}

// 8 fp32 -> bf16 hi8 + residual lo8, named scalars only (no address-taken locals)
__device__ __forceinline__ void cvt8(f32x4 a, f32x4 b, bf16x8& hi, bf16x8& lo) {
    const unsigned short h0 = f2bf(a[0]), h1 = f2bf(a[1]), h2 = f2bf(a[2]), h3 = f2bf(a[3]);
    const unsigned short h4 = f2bf(b[0]), h5 = f2bf(b[1]), h6 = f2bf(b[2]), h7 = f2bf(b[3]);
    uint4 H = make_uint4((unsigned)h0 | ((unsigned)h1 << 16), (unsigned)h2 | ((unsigned)h3 << 16),
                         (unsigned)h4 | ((unsigned)h5 << 16), (unsigned)h6 | ((unsigned)h7 << 16));
    uint4 L = make_uint4(pack2(a[0] - bf2f(h0), a[1] - bf2f(h1)),
                         pack2(a[2] - bf2f(h2), a[3] - bf2f(h3)),
                         pack2(b[0] - bf2f(h4), b[1] - bf2f(h5)),
                         pack2(b[2] - bf2f(h6), b[3] - bf2f(h7)));
    hi = __builtin_bit_cast(bf16x8, H);
    lo = __builtin_bit_cast(bf16x8, L);
}

// async 16B global -> LDS (linear dest; swizzle applied on the global source)
__device__ __forceinline__ void gload_lds16(const float* g, void* l) {
    __builtin_amdgcn_global_load_lds(
        (const __attribute__((address_space(1))) unsigned int*)g,
        (__attribute__((address_space(3))) unsigned int*)l, 16, 0, 0);
}

// DFS path-min walk; stores clipped z into packed LDS row (stride 127).
template<int T>
__device__ __forceinline__ void tree_walk(float qt, const float* __restrict__ srow,
                                          float* __restrict__ zrow, int part) {
    const float s  = srow[T];
    const float ql = fminf(qt, s);
    const float qr = fminf(qt, -s);
    if (((2 * T + 1) >> 5) == part) zrow[2 * T + 1] = fminf(fmaxf(ql, 0.f), 1.f);
    if (((2 * T + 2) >> 5) == part) zrow[2 * T + 2] = fminf(fmaxf(qr, 0.f), 1.f);
    if constexpr (2 * T + 1 < NSPLIT) tree_walk<2 * T + 1>(ql, srow, zrow, part);
    if constexpr (2 * T + 2 < NSPLIT) tree_walk<2 * T + 2>(qr, srow, zrow, part);
}

// LDS map (65536 B exactly -> 2 blocks/CU):
//   [0,16384)      xbuf0: x tile [128 rows][8 slots][16B], slot-swizzled s^=(row&7)
//   [16384,32768)  xbuf1
//   [32768,49152)  Bhi: [64 cols][16 slots][16B], slot-swizzled s^=(col&7)
//   [49152,65536)  Blo
// epilogue aliases: zarea per wave at wave*8128 (x region); warea 32768+wave*4160 (B region)
__global__ __launch_bounds__(NT, 2)
void lt_mfma4(const float* __restrict__ x, const float* __restrict__ A,
              float* __restrict__ out) {
    __shared__ __align__(16) unsigned char lds[65536];
    unsigned char* xb0 = lds;
    unsigned char* xb1 = lds + 16384;
    unsigned short* bhp = (unsigned short*)(lds + 32768);
    unsigned short* blp = (unsigned short*)(lds + 49152);

    const int tid  = threadIdx.x;
    const int wave = tid >> 6;
    const int lane = tid & 63;
    const int fr   = lane & 15;
    const int kb   = (lane >> 4) * 8;
    const int r0   = blockIdx.x * BM;
    const int m0   = wave * 32;

    // x staging roles: per instr j, unit u=j*256+tid -> row u>>3, slot (u&7)^(row&7)
    const float* xg = x + (size_t)r0 * KD;
    // B staging roles: 4 threads per row, 32 floats each
    const int brow = tid >> 2;
    const int bc   = tid & 3;
    const float* ag = A + (size_t)brow * KD + bc * 32;

    f32x4 acc[2][4];
#pragma unroll
    for (int i = 0; i < 2; ++i)
#pragma unroll
        for (int j = 0; j < 4; ++j) acc[i][j] = (f32x4)(0.f);

    // prologue: stage x tile 0
#pragma unroll
    for (int j = 0; j < 4; ++j) {
        const int u = j * 256 + tid;
        const int row = u >> 3;
        const int sp = (u & 7) ^ (row & 7);
        gload_lds16(xg + row * KD + sp * 4, xb0 + (size_t)u * 16);
    }

    const int m = fr & 7;
    const int u00 = (m0 + fr) * 8 + ((kb >> 2) ^ m);          // mf=0 slot base (xor 1 for +4)
    const int bo  = fr * 128 + 0;                              // filled per-σ below

#pragma unroll
    for (int q = 0; q < 4; ++q) {
        // ---- stage B quarter q (bf16 hi/lo, swizzled ds_write)
#pragma unroll
        for (int p = 0; p < 4; ++p) {
            f32x4 a = (f32x4)(0.f), b = (f32x4)(0.f);
            if (brow < NSPLIT) {
                a = *reinterpret_cast<const f32x4*>(ag + q * 128 + p * 8);
                b = *reinterpret_cast<const f32x4*>(ag + q * 128 + p * 8 + 4);
            }
            bf16x8 hi, lo;
            cvt8(a, b, hi, lo);
            const int sl = (bc * 4 + p) ^ (brow & 7);
            *reinterpret_cast<bf16x8*>(bhp + brow * 128 + sl * 8) = hi;
            *reinterpret_cast<bf16x8*>(blp + brow * 128 + sl * 8) = lo;
        }
        __syncthreads();   // B quarter ready; current x tile resident (vmcnt drained)

#pragma unroll
        for (int tl = 0; tl < 4; ++tl) {
            const int t = q * 4 + tl;
            // ---- issue next x tile first (flies under the MFMAs)
            if (t + 1 < 16) {
                unsigned char* nb = ((t + 1) & 1) ? xb1 : xb0;
                const float* xgt = xg + (t + 1) * 32;
#pragma unroll
                for (int j = 0; j < 4; ++j) {
                    const int u = j * 256 + tid;
                    const int row = u >> 3;
                    const int sp = (u & 7) ^ (row & 7);
                    gload_lds16(xgt + row * KD + sp * 4, nb + (size_t)u * 16);
                }
            }
            // ---- A frags from LDS (fp32, swizzled), convert in-reg
            const float* xbf = (const float*)((t & 1) ? xb1 : xb0);
            f32x4 va0 = *reinterpret_cast<const f32x4*>(xbf + u00 * 4);
            f32x4 vb0 = *reinterpret_cast<const f32x4*>(xbf + (u00 ^ 1) * 4);
            f32x4 va1 = *reinterpret_cast<const f32x4*>(xbf + (u00 + 128) * 4);
            f32x4 vb1 = *reinterpret_cast<const f32x4*>(xbf + ((u00 + 128) ^ 1) * 4);
            bf16x8 ah0, al0, ah1, al1;
            cvt8(va0, vb0, ah0, al0);
            cvt8(va1, vb1, ah1, al1);

            // ---- B frags (hi plane), swizzled
            const int sb = (tl * 4 + (kb >> 3)) ^ m;           // swizzled slot
            const int bof = fr * 128 + sb * 8;
            bf16x8 bv0 = *reinterpret_cast<const bf16x8*>(bhp + bof);
            bf16x8 bv1 = *reinterpret_cast<const bf16x8*>(bhp + bof + 2048);
            bf16x8 bv2 = *reinterpret_cast<const bf16x8*>(bhp + bof + 4096);
            bf16x8 bv3 = *reinterpret_cast<const bf16x8*>(bhp + bof + 6144);

            acc[0][0] = MFMA_B16(ah0, bv0, acc[0][0]);
            acc[1][0] = MFMA_B16(ah1, bv0, acc[1][0]);
            acc[0][1] = MFMA_B16(ah0, bv1, acc[0][1]);
            acc[1][1] = MFMA_B16(ah1, bv1, acc[1][1]);
            acc[0][2] = MFMA_B16(ah0, bv2, acc[0][2]);
            acc[1][2] = MFMA_B16(ah1, bv2, acc[1][2]);
            acc[0][3] = MFMA_B16(ah0, bv3, acc[0][3]);
            acc[1][3] = MFMA_B16(ah1, bv3, acc[1][3]);
            acc[0][0] = MFMA_B16(al0, bv0, acc[0][0]);
            acc[1][0] = MFMA_B16(al1, bv0, acc[1][0]);
            acc[0][1] = MFMA_B16(al0, bv1, acc[0][1]);
            acc[1][1] = MFMA_B16(al1, bv1, acc[1][1]);
            acc[0][2] = MFMA_B16(al0, bv2, acc[0][2]);
            acc[1][2] = MFMA_B16(al1, bv2, acc[1][2]);
            acc[0][3] = MFMA_B16(al0, bv3, acc[0][3]);
            acc[1][3] = MFMA_B16(al1, bv3, acc[1][3]);
            // hl: x_hi * B_lo
            bv0 = *reinterpret_cast<const bf16x8*>(blp + bof);
            bv1 = *reinterpret_cast<const bf16x8*>(blp + bof + 2048);
            bv2 = *reinterpret_cast<const bf16x8*>(blp + bof + 4096);
            bv3 = *reinterpret_cast<const bf16x8*>(blp + bof + 6144);
            acc[0][0] = MFMA_B16(ah0, bv0, acc[0][0]);
            acc[1][0] = MFMA_B16(ah1, bv0, acc[1][0]);
            acc[0][1] = MFMA_B16(ah0, bv1, acc[0][1]);
            acc[1][1] = MFMA_B16(ah1, bv1, acc[1][1]);
            acc[0][2] = MFMA_B16(ah0, bv2, acc[0][2]);
            acc[1][2] = MFMA_B16(ah1, bv2, acc[1][2]);
            acc[0][3] = MFMA_B16(ah0, bv3, acc[0][3]);
            acc[1][3] = MFMA_B16(ah1, bv3, acc[1][3]);

            __syncthreads();   // t+1 tile resident; xbuf[t&1] free for t+2
        }
    }

    // ---- epilogue: acc -> warea -> tree -> packed zarea -> coalesced global copy
    float* warea = (float*)(lds + 32768 + wave * 4160);   // [16][65]
    float* zw    = (float*)(lds + wave * 8128);           // [16][127] packed
    const int drow = (lane >> 4) * 4;
    const int trow = lane >> 2;
    const int part = lane & 3;

#pragma unroll
    for (int ph = 0; ph < 2; ++ph) {
#pragma unroll
        for (int nf = 0; nf < 4; ++nf)
#pragma unroll
            for (int rg = 0; rg < 4; ++rg)
                warea[(drow + rg) * 65 + nf * 16 + fr] = acc[ph][nf][rg];
        // wave-private region: in-wave DS ordering suffices, no barrier
        const float* srowp = warea + trow * 65;
        float* zrow = zw + trow * NNODES;
        if (part == 0) zrow[0] = 1.f;
        tree_walk<0>(1.f, srowp, zrow, part);

        // coalesced copy: 16 rows x 127 floats = 508 float4, 16B-aligned both sides
        float* og = out + (size_t)(r0 + m0 + ph * 16) * NNODES;
#pragma unroll
        for (int j = 0; j < 8; ++j) {
            const int idx = j * 64 + lane;
            if (idx < 508)
                *reinterpret_cast<f32x4*>(og + idx * 4) =
                    *reinterpret_cast<const f32x4*>((const float*)zw + idx * 4);
        }
    }
    (void)bo;
}

extern "C" void kernel_launch(void* const* d_in, const int* in_sizes, int n_in,
                              void* d_out, int out_size, void* d_ws, size_t ws_size,
                              hipStream_t stream) {
    const float* x = (const float*)d_in[0];   // [131072, 512]
    const float* A = (const float*)d_in[1];   // [63, 512]
    float* out = (float*)d_out;               // [131072, 127]
    const int nrows = in_sizes[0] / KD;       // 131072
    const int grid = nrows / BM;              // 1024 blocks, 2 resident/CU
    lt_mfma4<<<dim3(grid), dim3(NT), 0, stream>>>(x, A, out);
}

// Round 6
// 88.329 us; speedup vs baseline: 1.5583x; 1.0078x over previous
//
#include <hip/hip_runtime.h>
#include <hip/hip_bf16.h>
#include <cstdint>

#define KD 512
#define BM 128
#define NT 256
#define NSPLIT 63
#define NNODES 127
#define XWB 12288            // per-wave x region: 3 buffers x 4096 B
#define BH_OFF 49152         // B hi plane: [64 rows][16 slots][16B] = 16 KB
#define BL_OFF 65536         // B lo plane
                             // total LDS = 80 KB -> 2 blocks/CU

typedef __attribute__((ext_vector_type(8))) short bf16x8;
typedef __attribute__((ext_vector_type(4))) float f32x4;

#define MFMA_B16(a, b, c) __builtin_amdgcn_mfma_f32_16x16x32_bf16(a, b, c, 0, 0, 0)

static __device__ __forceinline__ unsigned short f2bf(float f) {
    return __builtin_bit_cast(unsigned short, __float2bfloat16(f));
}
static __device__ __forceinline__ float bf2f(unsigned short h) {
    return __builtin_bit_cast(float, (unsigned)h << 16);
}
static __device__ __forceinline__ unsigned pack2(float f0, float f1) {
    return (unsigned)f2bf(f0) | ((unsigned)f2bf(f1) << 16);
}

// 8 fp32 -> bf16 hi8 + residual lo8; named scalars only (stays in VGPRs)
static __device__ __forceinline__ void cvt8(f32x4 a, f32x4 b, bf16x8& hi, bf16x8& lo) {
    const unsigned short h0 = f2bf(a[0]), h1 = f2bf(a[1]), h2 = f2bf(a[2]), h3 = f2bf(a[3]);
    const unsigned short h4 = f2bf(b[0]), h5 = f2bf(b[1]), h6 = f2bf(b[2]), h7 = f2bf(b[3]);
    uint4 H = make_uint4((unsigned)h0 | ((unsigned)h1 << 16), (unsigned)h2 | ((unsigned)h3 << 16),
                         (unsigned)h4 | ((unsigned)h5 << 16), (unsigned)h6 | ((unsigned)h7 << 16));
    uint4 L = make_uint4(pack2(a[0] - bf2f(h0), a[1] - bf2f(h1)),
                         pack2(a[2] - bf2f(h2), a[3] - bf2f(h3)),
                         pack2(b[0] - bf2f(h4), b[1] - bf2f(h5)),
                         pack2(b[2] - bf2f(h6), b[3] - bf2f(h7)));
    hi = __builtin_bit_cast(bf16x8, H);
    lo = __builtin_bit_cast(bf16x8, L);
}

// async 16B global->LDS; dest is wave-uniform, HW scatters base + lane*16
static __device__ __forceinline__ void gload_lds16(const float* g, void* l) {
    __builtin_amdgcn_global_load_lds(
        (const __attribute__((address_space(1))) unsigned int*)g,
        (__attribute__((address_space(3))) unsigned int*)l, 16, 0, 0);
}

template<int N> static __device__ __forceinline__ void vmwait() {
    if constexpr (N == 8)      asm volatile("s_waitcnt vmcnt(8)" ::: "memory");
    else if constexpr (N == 4) asm volatile("s_waitcnt vmcnt(4)" ::: "memory");
    else                       asm volatile("s_waitcnt vmcnt(0)" ::: "memory");
}

// DFS path-min walk; clipped z into packed LDS row (stride 127), static indices
template<int T>
static __device__ __forceinline__ void tree_walk(float qt, const float* __restrict__ srow,
                                                 float* __restrict__ zrow, int part) {
    const float s  = srow[T];
    const float ql = fminf(qt, s);
    const float qr = fminf(qt, -s);
    if (((2 * T + 1) >> 5) == part) zrow[2 * T + 1] = fminf(fmaxf(ql, 0.f), 1.f);
    if (((2 * T + 2) >> 5) == part) zrow[2 * T + 2] = fminf(fmaxf(qr, 0.f), 1.f);
    if constexpr (2 * T + 1 < NSPLIT) tree_walk<2 * T + 1>(ql, srow, zrow, part);
    if constexpr (2 * T + 2 < NSPLIT) tree_walk<2 * T + 2>(qr, srow, zrow, part);
}

// stage B quarter Q: k-local slot swizzle sl = (slot ^ (row&7)) -> conflict-free frag reads
template<int Q>
static __device__ __forceinline__ void stage_B(const float* ag, bool bvalid,
                                               unsigned short* bhp, unsigned short* blp,
                                               int brow, int slb) {
#pragma unroll
    for (int p = 0; p < 4; ++p) {
        f32x4 a = (f32x4)(0.f), b = (f32x4)(0.f);
        if (bvalid) {
            a = *reinterpret_cast<const f32x4*>(ag + Q * 128 + p * 8);
            b = *reinterpret_cast<const f32x4*>(ag + Q * 128 + p * 8 + 4);
        }
        bf16x8 hi, lo;
        cvt8(a, b, hi, lo);
        const int sl = (slb + p) ^ (brow & 7);
        *reinterpret_cast<bf16x8*>(bhp + brow * 128 + sl * 8) = hi;
        *reinterpret_cast<bf16x8*>(blp + brow * 128 + sl * 8) = lo;
    }
}

// one 32-k tile, fully compile-time: counted vmcnt, per-wave triple buffer
template<int T>
static __device__ __forceinline__ void tiles(
        const float* xsrc, unsigned char* xw,
        unsigned short* bhp, unsigned short* blp,
        const float* ag, bool bvalid, int brow, int slb,
        int fr, int kb, int m, f32x4 (&acc)[2][4]) {
    if constexpr (T > 0 && (T & 3) == 0) {
        __builtin_amdgcn_s_barrier();          // all waves done reading quarter T/4-1
        stage_B<T / 4>(ag, bvalid, bhp, blp, brow, slb);
        asm volatile("s_waitcnt lgkmcnt(0)" ::: "memory");
        __builtin_amdgcn_s_barrier();          // quarter T/4 visible to all
    }
    __builtin_amdgcn_sched_barrier(0);         // pin: no gload hoist above prior reads
    if constexpr (T + 2 < 16) {
        constexpr int wb = (T + 2) % 3;
#pragma unroll
        for (int j = 0; j < 4; ++j)
            gload_lds16(xsrc + (T + 2) * 32 + j * 8 * KD, xw + wb * 4096 + j * 1024);
    }
    vmwait<(T <= 13 ? 8 : (T == 14 ? 4 : 0))>();  // tile T resident (own-wave loads)
    __builtin_amdgcn_sched_barrier(0);            // rule #18: no ds_read/MFMA hoist

    constexpr int rb = T % 3;
    const float* xbf = reinterpret_cast<const float*>(xw + rb * 4096);
    f32x4 va0 = *reinterpret_cast<const f32x4*>(xbf + fr * 32 + kb);
    f32x4 vb0 = *reinterpret_cast<const f32x4*>(xbf + fr * 32 + kb + 4);
    f32x4 va1 = *reinterpret_cast<const f32x4*>(xbf + (16 + fr) * 32 + kb);
    f32x4 vb1 = *reinterpret_cast<const f32x4*>(xbf + (16 + fr) * 32 + kb + 4);
    bf16x8 ah0, al0, ah1, al1;
    cvt8(va0, vb0, ah0, al0);
    cvt8(va1, vb1, ah1, al1);

    constexpr int tl = T & 3;
    const int sb  = (tl * 4 + (kb >> 3)) ^ m;
    const int bof = fr * 128 + sb * 8;
    bf16x8 bv0 = *reinterpret_cast<const bf16x8*>(bhp + bof);
    bf16x8 bv1 = *reinterpret_cast<const bf16x8*>(bhp + bof + 2048);
    bf16x8 bv2 = *reinterpret_cast<const bf16x8*>(bhp + bof + 4096);
    bf16x8 bv3 = *reinterpret_cast<const bf16x8*>(bhp + bof + 6144);

    acc[0][0] = MFMA_B16(ah0, bv0, acc[0][0]);
    acc[1][0] = MFMA_B16(ah1, bv0, acc[1][0]);
    acc[0][1] = MFMA_B16(ah0, bv1, acc[0][1]);
    acc[1][1] = MFMA_B16(ah1, bv1, acc[1][1]);
    acc[0][2] = MFMA_B16(ah0, bv2, acc[0][2]);
    acc[1][2] = MFMA_B16(ah1, bv2, acc[1][2]);
    acc[0][3] = MFMA_B16(ah0, bv3, acc[0][3]);
    acc[1][3] = MFMA_B16(ah1, bv3, acc[1][3]);
    acc[0][0] = MFMA_B16(al0, bv0, acc[0][0]);
    acc[1][0] = MFMA_B16(al1, bv0, acc[1][0]);
    acc[0][1] = MFMA_B16(al0, bv1, acc[0][1]);
    acc[1][1] = MFMA_B16(al1, bv1, acc[1][1]);
    acc[0][2] = MFMA_B16(al0, bv2, acc[0][2]);
    acc[1][2] = MFMA_B16(al1, bv2, acc[1][2]);
    acc[0][3] = MFMA_B16(al0, bv3, acc[0][3]);
    acc[1][3] = MFMA_B16(al1, bv3, acc[1][3]);
    // hl: x_hi * B_lo
    bv0 = *reinterpret_cast<const bf16x8*>(blp + bof);
    bv1 = *reinterpret_cast<const bf16x8*>(blp + bof + 2048);
    bv2 = *reinterpret_cast<const bf16x8*>(blp + bof + 4096);
    bv3 = *reinterpret_cast<const bf16x8*>(blp + bof + 6144);
    acc[0][0] = MFMA_B16(ah0, bv0, acc[0][0]);
    acc[1][0] = MFMA_B16(ah1, bv0, acc[1][0]);
    acc[0][1] = MFMA_B16(ah0, bv1, acc[0][1]);
    acc[1][1] = MFMA_B16(ah1, bv1, acc[1][1]);
    acc[0][2] = MFMA_B16(ah0, bv2, acc[0][2]);
    acc[1][2] = MFMA_B16(ah1, bv2, acc[1][2]);
    acc[0][3] = MFMA_B16(ah0, bv3, acc[0][3]);
    acc[1][3] = MFMA_B16(ah1, bv3, acc[1][3]);

    if constexpr (T + 1 < 16)
        tiles<T + 1>(xsrc, xw, bhp, blp, ag, bvalid, brow, slb, fr, kb, m, acc);
}

__global__ __launch_bounds__(NT, 2)
void lt_mfma5(const float* __restrict__ x, const float* __restrict__ A,
              float* __restrict__ out) {
    __shared__ __align__(16) unsigned char lds[81920];
    unsigned short* bhp = (unsigned short*)(lds + BH_OFF);
    unsigned short* blp = (unsigned short*)(lds + BL_OFF);

    const int tid  = threadIdx.x;
    const int wave = tid >> 6;
    const int lane = tid & 63;
    const int fr   = lane & 15;
    const int kb   = (lane >> 4) * 8;
    const int m    = fr & 7;
    const int r0   = blockIdx.x * BM;
    const int m0   = wave * 32;

    unsigned char* xw = lds + wave * XWB;                 // wave-private x buffers
    // per-lane global source: row = m0 + (lane>>3) (+ j*8 per instr), col = (lane&7)*4
    const float* xsrc = x + (size_t)(r0 + m0 + (lane >> 3)) * KD + (lane & 7) * 4;

    const int brow = tid >> 2;                            // B staging: 4 thr/row
    const int slb  = (tid & 3) * 4;
    const bool bvalid = brow < NSPLIT;
    const float* ag = A + (size_t)brow * KD + (tid & 3) * 32;

    f32x4 acc[2][4];
#pragma unroll
    for (int i = 0; i < 2; ++i)
#pragma unroll
        for (int j = 0; j < 4; ++j) acc[i][j] = (f32x4)(0.f);

    // prologue: issue x tiles 0,1 (per-wave), then stage B quarter 0
#pragma unroll
    for (int j = 0; j < 4; ++j)
        gload_lds16(xsrc + j * 8 * KD, xw + j * 1024);
#pragma unroll
    for (int j = 0; j < 4; ++j)
        gload_lds16(xsrc + 32 + j * 8 * KD, xw + 4096 + j * 1024);
    stage_B<0>(ag, bvalid, bhp, blp, brow, slb);
    asm volatile("s_waitcnt lgkmcnt(0)" ::: "memory");
    __builtin_amdgcn_s_barrier();

    tiles<0>(xsrc, xw, bhp, blp, ag, bvalid, brow, slb, fr, kb, m, acc);

    __syncthreads();   // drain everything; B region safe to reuse as warea

    // ---- epilogue: acc -> warea -> tree -> packed zw -> coalesced global copy
    float* warea = (float*)(lds + BH_OFF + wave * 4160);  // [16][65]
    float* zw    = (float*)(lds + wave * XWB);            // [16][127] packed (own x region)
    const int drow = (lane >> 4) * 4;
    const int trow = lane >> 2;
    const int part = lane & 3;

#pragma unroll
    for (int ph = 0; ph < 2; ++ph) {
#pragma unroll
        for (int nf = 0; nf < 4; ++nf)
#pragma unroll
            for (int rg = 0; rg < 4; ++rg)
                warea[(drow + rg) * 65 + nf * 16 + fr] = acc[ph][nf][rg];
        // wave-private areas; in-wave DS ordering suffices
        const float* srowp = warea + trow * 65;
        float* zrow = zw + trow * NNODES;
        if (part == 0) zrow[0] = 1.f;
        tree_walk<0>(1.f, srowp, zrow, part);

        float* og = out + (size_t)(r0 + m0 + ph * 16) * NNODES;
#pragma unroll
        for (int j = 0; j < 8; ++j) {
            const int idx = j * 64 + lane;
            if (idx < 508)
                *reinterpret_cast<f32x4*>(og + idx * 4) =
                    *reinterpret_cast<const f32x4*>((const float*)zw + idx * 4);
        }
    }
}

extern "C" void kernel_launch(void* const* d_in, const int* in_sizes, int n_in,
                              void* d_out, int out_size, void* d_ws, size_t ws_size,
                              hipStream_t stream) {
    const float* x = (const float*)d_in[0];   // [131072, 512]
    const float* A = (const float*)d_in[1];   // [63, 512]
    float* out = (float*)d_out;               // [131072, 127]
    const int nrows = in_sizes[0] / KD;       // 131072
    const int grid = nrows / BM;              // 1024 blocks, 2 resident/CU
    lt_mfma5<<<dim3(grid), dim3(NT), 0, stream>>>(x, A, out);
}

// Round 7
// 78.721 us; speedup vs baseline: 1.7485x; 1.1221x over previous
//
#include <hip/hip_runtime.h>
#include <hip/hip_bf16.h>
#include <cstdint>

#define KD 512
#define BM 256
#define NT 512
#define NSPLIT 63
#define NNODES 127
#define XW_OFF 0           // per-wave x: 2 buffers x 4096 B, 8 waves = 64 KB
#define BH_OFF 65536       // B hi plane: [64 rows][8 slots][16B] = 8 KB
#define BL_OFF 73728       // B lo plane = 8 KB; total LDS 81920 -> 2 blocks/CU

typedef __attribute__((ext_vector_type(8))) short bf16x8;
typedef __attribute__((ext_vector_type(4))) float f32x4;

#define MFMA_B16(a, b, c) __builtin_amdgcn_mfma_f32_16x16x32_bf16(a, b, c, 0, 0, 0)

static __device__ __forceinline__ unsigned short f2bf(float f) {
    return __builtin_bit_cast(unsigned short, __float2bfloat16(f));
}
static __device__ __forceinline__ float bf2f(unsigned short h) {
    return __builtin_bit_cast(float, (unsigned)h << 16);
}
static __device__ __forceinline__ unsigned pack2(float f0, float f1) {
    return (unsigned)f2bf(f0) | ((unsigned)f2bf(f1) << 16);
}

// 8 fp32 -> bf16 hi8 + residual lo8; named scalars only (stays in VGPRs)
static __device__ __forceinline__ void cvt8(f32x4 a, f32x4 b, bf16x8& hi, bf16x8& lo) {
    const unsigned short h0 = f2bf(a[0]), h1 = f2bf(a[1]), h2 = f2bf(a[2]), h3 = f2bf(a[3]);
    const unsigned short h4 = f2bf(b[0]), h5 = f2bf(b[1]), h6 = f2bf(b[2]), h7 = f2bf(b[3]);
    uint4 H = make_uint4((unsigned)h0 | ((unsigned)h1 << 16), (unsigned)h2 | ((unsigned)h3 << 16),
                         (unsigned)h4 | ((unsigned)h5 << 16), (unsigned)h6 | ((unsigned)h7 << 16));
    uint4 L = make_uint4(pack2(a[0] - bf2f(h0), a[1] - bf2f(h1)),
                         pack2(a[2] - bf2f(h2), a[3] - bf2f(h3)),
                         pack2(b[0] - bf2f(h4), b[1] - bf2f(h5)),
                         pack2(b[2] - bf2f(h6), b[3] - bf2f(h7)));
    hi = __builtin_bit_cast(bf16x8, H);
    lo = __builtin_bit_cast(bf16x8, L);
}

static __device__ __forceinline__ void gload_lds16(const float* g, void* l) {
    __builtin_amdgcn_global_load_lds(
        (const __attribute__((address_space(1))) unsigned int*)g,
        (__attribute__((address_space(3))) unsigned int*)l, 16, 0, 0);
}

template<int N> static __device__ __forceinline__ void vmwait() {
    if constexpr (N == 6)      asm volatile("s_waitcnt vmcnt(6)" ::: "memory");
    else if constexpr (N == 4) asm volatile("s_waitcnt vmcnt(4)" ::: "memory");
    else                       asm volatile("s_waitcnt vmcnt(0)" ::: "memory");
}

// DFS path-min; each lane (part8 = lane&7) stores nodes [part8*16, part8*16+16)
template<int T>
static __device__ __forceinline__ void tree_walk8(float qt, const float* __restrict__ srow,
                                                  float* __restrict__ zrow, int part8) {
    const float s  = srow[T];
    const float ql = fminf(qt, s);
    const float qr = fminf(qt, -s);
    if (((2 * T + 1) >> 4) == part8) zrow[2 * T + 1] = fminf(fmaxf(ql, 0.f), 1.f);
    if (((2 * T + 2) >> 4) == part8) zrow[2 * T + 2] = fminf(fmaxf(qr, 0.f), 1.f);
    if constexpr (2 * T + 1 < NSPLIT) tree_walk8<2 * T + 1>(ql, srow, zrow, part8);
    if constexpr (2 * T + 2 < NSPLIT) tree_walk8<2 * T + 2>(qr, srow, zrow, part8);
}

// write B chunk from pre-loaded regs: [64 rows][8 slots 16B], slot = bq ^ (row&7)
static __device__ __forceinline__ void write_B(unsigned short* bhp, unsigned short* blp,
                                               int brow, int sl, bool bvalid,
                                               f32x4 b0, f32x4 b1) {
    if (!bvalid) { b0 = (f32x4)(0.f); b1 = (f32x4)(0.f); }
    bf16x8 hi, lo;
    cvt8(b0, b1, hi, lo);
    *reinterpret_cast<bf16x8*>(bhp + brow * 64 + sl * 8) = hi;
    *reinterpret_cast<bf16x8*>(blp + brow * 64 + sl * 8) = lo;
}

// one 32-k tile; B chunk = 2 tiles; depth-1 x prefetch with exact vmcnt counting
template<int T>
static __device__ __forceinline__ void tiles(
        const float* xsrc, unsigned char* xw,
        unsigned short* bhp, unsigned short* blp,
        const float* ag, bool bvalid, int brow, int sl,
        int fr, int kb, int m, f32x4 (&acc)[2][4], f32x4& bn0, f32x4& bn1) {
    if constexpr ((T & 1) == 0) {
        if constexpr (T > 0) {                 // chunk boundary c = T/2
            __builtin_amdgcn_s_barrier();      // all waves done reading chunk c-1
            write_B(bhp, blp, brow, sl, bvalid, bn0, bn1);
            asm volatile("s_waitcnt lgkmcnt(0)" ::: "memory");
            __builtin_amdgcn_s_barrier();      // chunk c visible
        }
        if constexpr (T / 2 + 1 < 8) {         // issue B regs for chunk c+1 (flies ~2 tiles)
            __builtin_amdgcn_sched_barrier(0);
            if (bvalid) {
                bn0 = *reinterpret_cast<const f32x4*>(ag + (T / 2 + 1) * 64);
                bn1 = *reinterpret_cast<const f32x4*>(ag + (T / 2 + 1) * 64 + 4);
            }
            __builtin_amdgcn_sched_barrier(0);
        }
    }
    if constexpr (T + 1 < 16) {                // depth-1 x prefetch
        const float* xgt = xsrc + (T + 1) * 32;
        unsigned char* nb = xw + ((T + 1) & 1) * 4096;
#pragma unroll
        for (int j = 0; j < 4; ++j)
            gload_lds16(xgt + j * 8 * KD, nb + j * 1024);
    }
    __builtin_amdgcn_sched_barrier(0);
    vmwait<(T == 15) ? 0 : (((T & 1) == 0 && T < 14) ? 6 : 4)>();  // tile T resident
    __builtin_amdgcn_sched_barrier(0);

    // x frags: [32 rows][8 slots 16B], slot = kchunk ^ (row&7)
    const float* xbf = reinterpret_cast<const float*>(xw + (T & 1) * 4096);
    const int s0 = (kb >> 2) ^ m;
    f32x4 va0 = *reinterpret_cast<const f32x4*>(xbf + fr * 32 + s0 * 4);
    f32x4 vb0 = *reinterpret_cast<const f32x4*>(xbf + fr * 32 + (s0 ^ 1) * 4);
    f32x4 va1 = *reinterpret_cast<const f32x4*>(xbf + (16 + fr) * 32 + s0 * 4);
    f32x4 vb1 = *reinterpret_cast<const f32x4*>(xbf + (16 + fr) * 32 + (s0 ^ 1) * 4);
    bf16x8 ah0, al0, ah1, al1;
    cvt8(va0, vb0, ah0, al0);
    cvt8(va1, vb1, ah1, al1);

    const int sb  = (((T & 1) * 4) + (kb >> 3)) ^ m;
    const int bof = fr * 64 + sb * 8;
    bf16x8 bv0 = *reinterpret_cast<const bf16x8*>(bhp + bof);
    bf16x8 bv1 = *reinterpret_cast<const bf16x8*>(bhp + bof + 1024);
    bf16x8 bv2 = *reinterpret_cast<const bf16x8*>(bhp + bof + 2048);
    bf16x8 bv3 = *reinterpret_cast<const bf16x8*>(bhp + bof + 3072);

    acc[0][0] = MFMA_B16(ah0, bv0, acc[0][0]);
    acc[1][0] = MFMA_B16(ah1, bv0, acc[1][0]);
    acc[0][1] = MFMA_B16(ah0, bv1, acc[0][1]);
    acc[1][1] = MFMA_B16(ah1, bv1, acc[1][1]);
    acc[0][2] = MFMA_B16(ah0, bv2, acc[0][2]);
    acc[1][2] = MFMA_B16(ah1, bv2, acc[1][2]);
    acc[0][3] = MFMA_B16(ah0, bv3, acc[0][3]);
    acc[1][3] = MFMA_B16(ah1, bv3, acc[1][3]);
    acc[0][0] = MFMA_B16(al0, bv0, acc[0][0]);
    acc[1][0] = MFMA_B16(al1, bv0, acc[1][0]);
    acc[0][1] = MFMA_B16(al0, bv1, acc[0][1]);
    acc[1][1] = MFMA_B16(al1, bv1, acc[1][1]);
    acc[0][2] = MFMA_B16(al0, bv2, acc[0][2]);
    acc[1][2] = MFMA_B16(al1, bv2, acc[1][2]);
    acc[0][3] = MFMA_B16(al0, bv3, acc[0][3]);
    acc[1][3] = MFMA_B16(al1, bv3, acc[1][3]);
    // hl: x_hi * B_lo
    bv0 = *reinterpret_cast<const bf16x8*>(blp + bof);
    bv1 = *reinterpret_cast<const bf16x8*>(blp + bof + 1024);
    bv2 = *reinterpret_cast<const bf16x8*>(blp + bof + 2048);
    bv3 = *reinterpret_cast<const bf16x8*>(blp + bof + 3072);
    acc[0][0] = MFMA_B16(ah0, bv0, acc[0][0]);
    acc[1][0] = MFMA_B16(ah1, bv0, acc[1][0]);
    acc[0][1] = MFMA_B16(ah0, bv1, acc[0][1]);
    acc[1][1] = MFMA_B16(ah1, bv1, acc[1][1]);
    acc[0][2] = MFMA_B16(ah0, bv2, acc[0][2]);
    acc[1][2] = MFMA_B16(ah1, bv2, acc[1][2]);
    acc[0][3] = MFMA_B16(ah0, bv3, acc[0][3]);
    acc[1][3] = MFMA_B16(ah1, bv3, acc[1][3]);

    if constexpr (T + 1 < 16)
        tiles<T + 1>(xsrc, xw, bhp, blp, ag, bvalid, brow, sl, fr, kb, m, acc, bn0, bn1);
}

__global__ __launch_bounds__(NT, 4)
void lt_mfma6(const float* __restrict__ x, const float* __restrict__ A,
              float* __restrict__ out) {
    __shared__ __align__(16) unsigned char lds[81920];
    unsigned short* bhp = (unsigned short*)(lds + BH_OFF);
    unsigned short* blp = (unsigned short*)(lds + BL_OFF);

    const int tid  = threadIdx.x;
    const int wave = tid >> 6;
    const int lane = tid & 63;
    const int fr   = lane & 15;
    const int kb   = (lane >> 4) * 8;
    const int m    = fr & 7;
    const int r0   = blockIdx.x * BM;
    const int m0   = wave * 32;

    unsigned char* xw = lds + XW_OFF + wave * 8192;       // wave-private x dbuf
    // gload source: row = m0 + j*8 + (lane>>3); col kchunk pre-swizzled so LDS is linear
    const float* xsrc = x + (size_t)(r0 + m0 + (lane >> 3)) * KD
                          + (((lane & 7) ^ ((lane >> 3) & 7)) << 2);

    const int brow = tid >> 3;                            // B staging: 8 thr/row
    const int bq   = tid & 7;
    const int sl   = bq ^ (brow & 7);
    const bool bvalid = brow < NSPLIT;
    const float* ag = A + (size_t)brow * KD + bq * 8;

    f32x4 acc[2][4];
#pragma unroll
    for (int i = 0; i < 2; ++i)
#pragma unroll
        for (int j = 0; j < 4; ++j) acc[i][j] = (f32x4)(0.f);

    f32x4 bn0 = (f32x4)(0.f), bn1 = (f32x4)(0.f);

    // prologue: issue x tile 0; load+write B chunk 0
#pragma unroll
    for (int j = 0; j < 4; ++j)
        gload_lds16(xsrc + j * 8 * KD, xw + j * 1024);
    if (bvalid) {
        bn0 = *reinterpret_cast<const f32x4*>(ag);
        bn1 = *reinterpret_cast<const f32x4*>(ag + 4);
    }
    write_B(bhp, blp, brow, sl, bvalid, bn0, bn1);        // compiler drains vmcnt for B regs
    asm volatile("s_waitcnt lgkmcnt(0)" ::: "memory");
    __builtin_amdgcn_s_barrier();

    tiles<0>(xsrc, xw, bhp, blp, ag, bvalid, brow, sl, fr, kb, m, acc, bn0, bn1);

    // ---- epilogue: wave-private (own x region); 2 acc-phases x 2 sub-phases of 8 rows
    float* xwf   = reinterpret_cast<float*>(xw);
    float* warea = xwf;                                   // [8][65] = 520 floats
    float* zw    = xwf + 520;                             // [8][127] = 1016 floats
    const int g     = lane >> 4;                          // acc row group
    const int o     = lane >> 3;                          // epilogue row (octet)
    const int part8 = lane & 7;

#pragma unroll
    for (int ph = 0; ph < 2; ++ph) {
#pragma unroll
        for (int s = 0; s < 2; ++s) {
            if ((lane >> 5) == s) {
#pragma unroll
                for (int nf = 0; nf < 4; ++nf)
#pragma unroll
                    for (int rg = 0; rg < 4; ++rg)
                        warea[((g & 1) * 4 + rg) * 65 + nf * 16 + fr] = acc[ph][nf][rg];
            }
            // same-wave LDS ordering via lgkmcnt (compiler-tracked)
            const float* srow = warea + o * 65;
            float* zrow = zw + o * NNODES;
            if (part8 == 0) zrow[0] = 1.f;
            tree_walk8<0>(1.f, srow, zrow, part8);

            float* og = out + (size_t)(r0 + m0 + ph * 16 + s * 8) * NNODES;
#pragma unroll
            for (int j = 0; j < 4; ++j) {
                const int idx = j * 64 + lane;
                if (idx < 254)
                    *reinterpret_cast<f32x4*>(og + idx * 4) =
                        *reinterpret_cast<const f32x4*>(zw + idx * 4);
            }
        }
    }
}

extern "C" void kernel_launch(void* const* d_in, const int* in_sizes, int n_in,
                              void* d_out, int out_size, void* d_ws, size_t ws_size,
                              hipStream_t stream) {
    const float* x = (const float*)d_in[0];   // [131072, 512]
    const float* A = (const float*)d_in[1];   // [63, 512]
    float* out = (float*)d_out;               // [131072, 127]
    const int nrows = in_sizes[0] / KD;       // 131072
    const int grid = nrows / BM;              // 512 blocks = 2/CU, 16 waves/CU
    lt_mfma6<<<dim3(grid), dim3(NT), 0, stream>>>(x, A, out);
}